// Round 22
// baseline (278.702 us; speedup 1.0000x reference)
//
#include <hip/hip_runtime.h>
#include <hip/hip_bf16.h>

// ---------------------------------------------------------------------------
// MultiheadAttention fused pipeline for MI355X (gfx950)
// B=2, S=S'=2048, H=16, D_MODEL=1024, dk=dv=64
// outputs: out [2,2048,1024] fp32, attn [2,16,2048,2048] fp32 (concat in d_out)
// ---------------------------------------------------------------------------

typedef __bf16 bf16x8 __attribute__((ext_vector_type(8)));
typedef __bf16 bf16x4 __attribute__((ext_vector_type(4)));
typedef float  f32x4  __attribute__((ext_vector_type(4)));
typedef float  f32x16 __attribute__((ext_vector_type(16)));

#define NUM_HEAD 16
#define SEQ 2048
#define DMODEL 1024
#define DK 64
#define MROWS 4096      // B*S
#define LOG2E 1.44269504088896340736f

__device__ __forceinline__ void gload_lds16(const void* g, void* l) {
    __builtin_amdgcn_global_load_lds((const __attribute__((address_space(1))) void*)g,
                                     (__attribute__((address_space(3))) void*)l, 16, 0, 0);
}

// ---------------------------------------------------------------------------
// Fused LayerNorm(query)->bf16  +  all fp32->bf16 casts, one dispatch.
// ---------------------------------------------------------------------------
__global__ __launch_bounds__(256) void ln_cast(const float* __restrict__ x,
                                               const float* __restrict__ g,
                                               const float* __restrict__ bt,
                                               __bf16* __restrict__ y,
                                               const float* __restrict__ key,
                                               const float* __restrict__ value,
                                               const float* __restrict__ wq,
                                               const float* __restrict__ wk,
                                               const float* __restrict__ wv,
                                               const float* __restrict__ wo,
                                               __bf16* kb, __bf16* vb, __bf16* wqb,
                                               __bf16* wkb, __bf16* wvb, __bf16* wob) {
    int tid = threadIdx.x;
    if (blockIdx.x < 4096) {
        int row = blockIdx.x;
        __shared__ float red[2][4];
        float4 v = ((const float4*)(x + (size_t)row * DMODEL))[tid];
        float s  = v.x + v.y + v.z + v.w;
        float sq = v.x * v.x + v.y * v.y + v.z * v.z + v.w * v.w;
        #pragma unroll
        for (int o = 32; o; o >>= 1) { s += __shfl_xor(s, o, 64); sq += __shfl_xor(sq, o, 64); }
        int wv_ = tid >> 6;
        if ((tid & 63) == 0) { red[0][wv_] = s; red[1][wv_] = sq; }
        __syncthreads();
        s  = red[0][0] + red[0][1] + red[0][2] + red[0][3];
        sq = red[1][0] + red[1][1] + red[1][2] + red[1][3];
        float mu  = s * (1.0f / DMODEL);
        float var = sq * (1.0f / DMODEL) - mu * mu;
        float rs  = rsqrtf(var + 1e-6f);
        float4 gg = ((const float4*)g)[tid];
        float4 bb = ((const float4*)bt)[tid];
        bf16x4 o;
        o[0] = (__bf16)((v.x - mu) * rs * gg.x + bb.x);
        o[1] = (__bf16)((v.y - mu) * rs * gg.y + bb.y);
        o[2] = (__bf16)((v.z - mu) * rs * gg.z + bb.z);
        o[3] = (__bf16)((v.w - mu) * rs * gg.w + bb.w);
        *(bf16x4*)&y[(size_t)row * DMODEL + tid * 4] = o;
    } else {
        int i = (blockIdx.x - 4096) * 256 + tid;    // float4 index, [0, 3145728)
        const float* src; __bf16* dst; int off;
        if (i < 1048576)      { src = key;   dst = kb;  off = i; }
        else if (i < 2097152) { src = value; dst = vb;  off = i - 1048576; }
        else if (i < 2359296) { src = wq;    dst = wqb; off = i - 2097152; }
        else if (i < 2621440) { src = wk;    dst = wkb; off = i - 2359296; }
        else if (i < 2883584) { src = wv;    dst = wvb; off = i - 2621440; }
        else                  { src = wo;    dst = wob; off = i - 2883584; }
        float4 v = ((const float4*)src)[off];
        bf16x4 o = {(__bf16)v.x, (__bf16)v.y, (__bf16)v.z, (__bf16)v.w};
        *(bf16x4*)&dst[(size_t)off * 4] = o;
    }
}

// ---------------------------------------------------------------------------
// Shared BK=64 XOR-swizzled GEMM K-loop (verified r15 core).
// ---------------------------------------------------------------------------
__device__ __forceinline__ void gemm_core64(const __bf16* __restrict__ Arow,
                                            const __bf16* __restrict__ Brow,
                                            __bf16 (*As)[64], __bf16 (*Bs)[64],
                                            int tid, int wr, int wc, int lr, int lg,
                                            f32x4 (&acc)[4][2]) {
    for (int kt = 0; kt < 1024; kt += 64) {
        __syncthreads();   // prior iter's LDS reads done
        #pragma unroll
        for (int c = 0; c < 4; ++c) {      // A: 128 rows x 64 cols
            int row = c * 32 + (tid >> 3);
            int col = ((tid & 7) ^ (row & 7)) * 8;
            gload_lds16(&Arow[(size_t)row * 1024 + kt + col], &As[row][(tid & 7) * 8]);
        }
        #pragma unroll
        for (int c = 0; c < 2; ++c) {      // B: 64 rows x 64 cols
            int row = c * 32 + (tid >> 3);
            int col = ((tid & 7) ^ (row & 7)) * 8;
            gload_lds16(&Brow[(size_t)row * 1024 + kt + col], &Bs[row][(tid & 7) * 8]);
        }
        __syncthreads();   // drains vmcnt+lgkm
        #pragma unroll
        for (int kk = 0; kk < 2; ++kk) {
            bf16x8 af[4], bg[2];
            #pragma unroll
            for (int m = 0; m < 4; ++m) {
                int row = wr + m * 16 + lr;
                int slot = (kk * 4 + lg) ^ (row & 7);
                af[m] = *(const bf16x8*)&As[row][slot * 8];
            }
            #pragma unroll
            for (int n = 0; n < 2; ++n) {
                int row = wc + n * 16 + lr;
                int slot = (kk * 4 + lg) ^ (row & 7);
                bg[n] = *(const bf16x8*)&Bs[row][slot * 8];
            }
            #pragma unroll
            for (int m = 0; m < 4; ++m)
                #pragma unroll
                for (int n = 0; n < 2; ++n)
                    acc[m][n] = __builtin_amdgcn_mfma_f32_16x16x32_bf16(af[m], bg[n], acc[m][n], 0, 0, 0);
        }
    }
}

// ---------------------------------------------------------------------------
// Fused Q/K/V projections, 128x64 tiles -> 3 x 512 = 1536 blocks (6/CU),
// XCD-chunked block swizzle.  mode 0: Q scaled (1/8)*log2e; 1: K; 2: V^T.
// ---------------------------------------------------------------------------
__global__ __launch_bounds__(256) void qkv_proj(const __bf16* __restrict__ qn,
                                                const __bf16* __restrict__ kb,
                                                const __bf16* __restrict__ vb,
                                                const __bf16* __restrict__ wqb,
                                                const __bf16* __restrict__ wkb,
                                                const __bf16* __restrict__ wvb,
                                                __bf16* __restrict__ Qp,
                                                __bf16* __restrict__ Kp,
                                                __bf16* __restrict__ Vt) {
    __shared__ __bf16 As[128][64];   // 16 KB
    __shared__ __bf16 Bs[64][64];    //  8 KB
    int bid = blockIdx.x;
    int wgid = (bid & 7) * 192 + (bid >> 3);  // XCD-chunked (1536/8 = 192)
    int mode = wgid >> 9;                     // 0,1,2
    int t = wgid & 511;
    int tm = t >> 4, tn = t & 15;             // 32 x 16 tiles (M=4096, N=1024)
    int tid = threadIdx.x, lane = tid & 63, wv = tid >> 6;
    int wr = (wv >> 1) * 64, wc = (wv & 1) * 32;
    int lr = lane & 15, lg = lane >> 4;

    const __bf16* A = (mode == 0) ? qn : (mode == 1) ? kb : vb;
    const __bf16* W = (mode == 0) ? wqb : (mode == 1) ? wkb : wvb;

    f32x4 acc[4][2] = {};
    gemm_core64(A + (size_t)(tm * 128) * 1024, W + (size_t)(tn * 64) * 1024,
                As, Bs, tid, wr, wc, lr, lg, acc);

    if (mode < 2) {
        float scale = (mode == 0) ? (0.125f * LOG2E) : 1.0f;
        __bf16* C = (mode == 0) ? Qp : Kp;
        #pragma unroll
        for (int m = 0; m < 4; ++m)
            #pragma unroll
            for (int n = 0; n < 2; ++n)
                #pragma unroll
                for (int r = 0; r < 4; ++r) {
                    int grow = tm * 128 + wr + m * 16 + lg * 4 + r;
                    int gcol = tn * 64 + wc + n * 16 + lr;
                    int b = grow >> 11, ss = grow & 2047, h = gcol >> 6, d = gcol & 63;
                    C[((size_t)(b * NUM_HEAD + h) * SEQ + ss) * DK + d] = (__bf16)(acc[m][n][r] * scale);
                }
    } else {
        #pragma unroll
        for (int m = 0; m < 4; ++m)
            #pragma unroll
            for (int n = 0; n < 2; ++n)
                #pragma unroll
                for (int r = 0; r < 4; ++r) {
                    int grow = tm * 128 + wr + m * 16 + lg * 4 + r;
                    int gcol = tn * 64 + wc + n * 16 + lr;
                    int b = grow >> 11, ss = grow & 2047, h = gcol >> 6, d = gcol & 63;
                    Vt[((size_t)(b * NUM_HEAD + h) * DK + d) * SEQ + ss] = (__bf16)acc[m][n][r];
                }
    }
}

// ---------------------------------------------------------------------------
// Output projection + residual, 128x64 tiles -> 512 blocks (2/CU), XCD swz.
// ---------------------------------------------------------------------------
__global__ __launch_bounds__(256) void out_gemm(const __bf16* __restrict__ A,
                                                const __bf16* __restrict__ Bw,
                                                const float* __restrict__ residual,
                                                float* __restrict__ out) {
    __shared__ __bf16 As[128][64];
    __shared__ __bf16 Bs[64][64];
    int bid = blockIdx.x;
    int wgid = (bid & 7) * 64 + (bid >> 3);   // XCD-chunked
    int tm = wgid >> 4, tn = wgid & 15;
    int tid = threadIdx.x, lane = tid & 63, wv = tid >> 6;
    int wr = (wv >> 1) * 64, wc = (wv & 1) * 32;
    int lr = lane & 15, lg = lane >> 4;

    f32x4 acc[4][2] = {};
    gemm_core64(A + (size_t)(tm * 128) * 1024, Bw + (size_t)(tn * 64) * 1024,
                As, Bs, tid, wr, wc, lr, lg, acc);

    #pragma unroll
    for (int m = 0; m < 4; ++m)
        #pragma unroll
        for (int n = 0; n < 2; ++n)
            #pragma unroll
            for (int r = 0; r < 4; ++r) {
                int grow = tm * 128 + wr + m * 16 + lg * 4 + r;
                int gcol = tn * 64 + wc + n * 16 + lr;
                size_t idx = (size_t)grow * DMODEL + gcol;
                out[idx] = acc[m][n][r] + residual[idx];
            }
}

// ---------------------------------------------------------------------------
// Attention, LDS-staged K/V (attn8), m==0 softmax, 48 KB LDS -> 3 blocks/CU.
//   Ks[2][128][64] (32 KB, double-buffered) + Vs[64][128] (16 KB, SINGLE).
//   V(c+1) staged AFTER the trailing barrier (all V reads of round c done);
//   its latency is drained at the next leading barrier -- covered by the
//   third co-resident block (the point of the occupancy increase).
// Pass A: r19 128-key/16-round form (Ks only).
// gload_lds rule: per-wave LDS dest contiguous lane*16 (m104).
// Swizzle: phys slot = logical ^ (row&7) on both source and read (rule #21).
// ---------------------------------------------------------------------------
__global__ __launch_bounds__(256, 3) void attn8(const __bf16* __restrict__ Qp,
                                                const __bf16* __restrict__ Kp,
                                                const __bf16* __restrict__ Vt,
                                                float* __restrict__ attn_out,
                                                __bf16* __restrict__ out_heads) {
    __shared__ __bf16 Ks[2][128][64];   // 32 KB
    __shared__ __bf16 Vs[64][128];      // 16 KB (single buffer)

    int bid = blockIdx.x;
    int wid = (bid & 7) * 64 + (bid >> 3);    // 512 blocks, XCD-chunked (512%8==0)
    int bh = wid >> 4;                        // [0,32)
    int qbase = (wid & 15) * 128;             // block q-rows [qbase, qbase+128)
    int tid = threadIdx.x, lane = tid & 63, wv = tid >> 6;
    int l31 = lane & 31, hi = lane >> 5;
    int qw = qbase + wv * 32;                 // wave's 32 q-rows

    const __bf16* Qh = Qp + ((size_t)bh * SEQ + qw) * DK;
    const __bf16* Kh = Kp + (size_t)bh * SEQ * DK;
    const __bf16* Vh = Vt + (size_t)bh * DK * SEQ;

    bf16x8 qf[4];
    #pragma unroll
    for (int s = 0; s < 4; ++s)
        qf[s] = *(const bf16x8*)&Qh[(size_t)l31 * DK + s * 16 + hi * 8];

    // ---- staging lambdas; per-wave LDS dest = lane*16 contiguous ----
    int krow = tid >> 3, ksc = tid & 7;       // K: 32 rows/step x 8 slots
    auto stageK = [&](int buf, int kc) {
        #pragma unroll
        for (int j = 0; j < 4; ++j) {
            int row = j * 32 + krow;
            gload_lds16(&Kh[(size_t)(kc + row) * DK + ((ksc ^ (row & 7)) * 8)],
                        &Ks[buf][row][ksc * 8]);
        }
    };
    int vrow16 = tid >> 4, vslot = tid & 15;  // V: 16 rows/step x 16 slots
    auto stageV = [&](int kc) {
        #pragma unroll
        for (int j = 0; j < 4; ++j) {
            int row = j * 16 + vrow16;
            gload_lds16(&Vh[(size_t)row * SEQ + kc + ((vslot ^ (row & 7)) * 8)],
                        &Vs[row][vslot * 8]);
        }
    };
    auto readK = [&](int buf, int row, int s) -> bf16x8 {
        int slot = (2 * s + hi) ^ (row & 7);
        return *(const bf16x8*)&Ks[buf][row][slot * 8];
    };
    auto readV = [&](int drow, int g) -> bf16x8 {
        int slot = g ^ (drow & 7);
        return *(const bf16x8*)&Vs[drow][slot * 8];
    };

    // ---- pass A: lsum over all 2048 keys (m == 0), 128-key chunks ----
    float lsum = 0.f;
    auto tileA = [&](int buf, int toff) {
        bf16x8 kf[4];
        #pragma unroll
        for (int s = 0; s < 4; ++s) kf[s] = readK(buf, toff + l31, s);
        f32x16 dd;
        #pragma unroll
        for (int r = 0; r < 16; ++r) dd[r] = 0.f;
        __builtin_amdgcn_s_setprio(1);
        #pragma unroll
        for (int s = 0; s < 4; ++s)
            dd = __builtin_amdgcn_mfma_f32_32x32x16_bf16(kf[s], qf[s], dd, 0, 0, 0);
        __builtin_amdgcn_s_setprio(0);
        float es[4] = {0.f, 0.f, 0.f, 0.f};
        #pragma unroll
        for (int r = 0; r < 16; ++r) es[r & 3] += exp2f(dd[r]);
        lsum += (es[0] + es[1]) + (es[2] + es[3]);
    };

    stageK(0, 0);
    for (int c = 0; c < 16; ++c) {
        __syncthreads();                       // stage of buf (c&1) complete
        if (c + 1 < 16) stageK((c + 1) & 1, (c + 1) * 128);
        tileA(c & 1, 0);
        tileA(c & 1, 32);
        tileA(c & 1, 64);
        tileA(c & 1, 96);
        __syncthreads();                       // reads done before re-stage
    }
    lsum += __shfl_xor(lsum, 32, 64);          // merge interleaved key-halves
    float invl = 1.0f / lsum;

    // ---- pass B: normalized P write + PV (single-buffer V) ----
    float* attn_base = attn_out + ((size_t)bh * SEQ + qw) * SEQ;
    f32x16 o0, o1;
    #pragma unroll
    for (int r = 0; r < 16; ++r) { o0[r] = 0.f; o1[r] = 0.f; }

    auto tileB = [&](int buf, int kglob, int toff) {
        bf16x8 kf[4];
        #pragma unroll
        for (int s = 0; s < 4; ++s) kf[s] = readK(buf, toff + l31, s);
        f32x16 dd;
        #pragma unroll
        for (int r = 0; r < 16; ++r) dd[r] = 0.f;
        __builtin_amdgcn_s_setprio(1);
        #pragma unroll
        for (int s = 0; s < 4; ++s)
            dd = __builtin_amdgcn_mfma_f32_32x32x16_bf16(kf[s], qf[s], dd, 0, 0, 0);
        __builtin_amdgcn_s_setprio(0);

        int gb = toff >> 3;   // V slot base within chunk (0,4,8,12)
        bf16x8 vf00 = readV(l31,      gb + hi);
        bf16x8 vf01 = readV(32 + l31, gb + hi);
        bf16x8 vf10 = readV(l31,      gb + 2 + hi);
        bf16x8 vf11 = readV(32 + l31, gb + 2 + hi);

        float p[16];
        #pragma unroll
        for (int r = 0; r < 16; ++r) p[r] = exp2f(dd[r]) * invl;

        int k0 = kglob + toff;
        #pragma unroll
        for (int q4 = 0; q4 < 4; ++q4) {
            f32x4 v4 = {p[4 * q4], p[4 * q4 + 1], p[4 * q4 + 2], p[4 * q4 + 3]};
            *(f32x4*)&attn_base[(size_t)l31 * SEQ + k0 + 8 * q4 + 4 * hi] = v4;
        }

        unsigned int w[8];
        #pragma unroll
        for (int i = 0; i < 8; ++i) {
            union { __bf16 h[2]; unsigned int u; } bw;
            bw.h[0] = (__bf16)p[2 * i];
            bw.h[1] = (__bf16)p[2 * i + 1];
            w[i] = bw.u;
        }
        __builtin_amdgcn_s_setprio(1);
        {   // slot 0 (keys k0..k0+15)
            unsigned int a0 = w[0], a1 = w[1], a2 = w[2], a3 = w[3];
            asm volatile("v_permlane32_swap_b32 %0, %1" : "+v"(a0), "+v"(a2));
            asm volatile("v_permlane32_swap_b32 %0, %1" : "+v"(a1), "+v"(a3));
            union { unsigned int u[4]; bf16x8 v; } pa;
            pa.u[0] = a0; pa.u[1] = a1; pa.u[2] = a2; pa.u[3] = a3;
            o0 = __builtin_amdgcn_mfma_f32_32x32x16_bf16(pa.v, vf00, o0, 0, 0, 0);
            o1 = __builtin_amdgcn_mfma_f32_32x32x16_bf16(pa.v, vf01, o1, 0, 0, 0);
        }
        {   // slot 1 (keys k0+16..k0+31)
            unsigned int a0 = w[4], a1 = w[5], a2 = w[6], a3 = w[7];
            asm volatile("v_permlane32_swap_b32 %0, %1" : "+v"(a0), "+v"(a2));
            asm volatile("v_permlane32_swap_b32 %0, %1" : "+v"(a1), "+v"(a3));
            union { unsigned int u[4]; bf16x8 v; } pa;
            pa.u[0] = a0; pa.u[1] = a1; pa.u[2] = a2; pa.u[3] = a3;
            o0 = __builtin_amdgcn_mfma_f32_32x32x16_bf16(pa.v, vf10, o0, 0, 0, 0);
            o1 = __builtin_amdgcn_mfma_f32_32x32x16_bf16(pa.v, vf11, o1, 0, 0, 0);
        }
        __builtin_amdgcn_s_setprio(0);
    };

    stageK(0, 0);
    stageV(0);
    for (int c = 0; c < 16; ++c) {
        __syncthreads();                       // K(c) and V(c) staged complete
        if (c + 1 < 16) stageK((c + 1) & 1, (c + 1) * 128);
        tileB(c & 1, c * 128, 0);
        tileB(c & 1, c * 128, 32);
        tileB(c & 1, c * 128, 64);
        tileB(c & 1, c * 128, 96);
        __syncthreads();                       // all reads of Vs/Ks done
        if (c + 1 < 16) stageV((c + 1) * 128); // overwrite single V buffer
    }

    // ---- O write: P already normalized in tileB -> no invl here ----
    int b = bh >> 4, h = bh & 15;
    #pragma unroll
    for (int r = 0; r < 16; ++r) {
        int q = (r & 3) + 8 * (r >> 2) + 4 * hi;
        __bf16* orow = &out_heads[((size_t)(b * SEQ + qw + q)) * DMODEL + h * DK];
        orow[l31]      = (__bf16)o0[r];
        orow[32 + l31] = (__bf16)o1[r];
    }
}

// ---------------------------------------------------------------------------
extern "C" void kernel_launch(void* const* d_in, const int* in_sizes, int n_in,
                              void* d_out, int out_size, void* d_ws, size_t ws_size,
                              hipStream_t stream) {
    const float* query = (const float*)d_in[0];
    const float* key   = (const float*)d_in[1];
    const float* value = (const float*)d_in[2];
    const float* w_q   = (const float*)d_in[3];
    const float* w_k   = (const float*)d_in[4];
    const float* w_v   = (const float*)d_in[5];
    const float* w_o   = (const float*)d_in[6];
    const float* lng   = (const float*)d_in[7];
    const float* lnb   = (const float*)d_in[8];

    char* ws = (char*)d_ws;
    __bf16* qn  = (__bf16*)(ws);                    // 8 MB  LN(query) bf16
    __bf16* kb  = (__bf16*)(ws + ( 8u << 20));      // 8 MB  key bf16
    __bf16* vb  = (__bf16*)(ws + (16u << 20));      // 8 MB  value bf16
    __bf16* wqb = (__bf16*)(ws + (24u << 20));      // 2 MB
    __bf16* wkb = (__bf16*)(ws + (26u << 20));      // 2 MB
    __bf16* wvb = (__bf16*)(ws + (28u << 20));      // 2 MB
    __bf16* wob = (__bf16*)(ws + (30u << 20));      // 2 MB
    __bf16* Qp  = (__bf16*)(ws + (32u << 20));      // 8 MB  [b,h,s,64] (x(1/8)*log2e)
    __bf16* Kp  = (__bf16*)(ws + (40u << 20));      // 8 MB  [b,h,s,64]
    __bf16* Vt  = (__bf16*)(ws + (48u << 20));      // 8 MB  [b,h,64,s']
    __bf16* oh  = (__bf16*)(ws + (56u << 20));      // 8 MB  attention out [4096,1024]

    float* out  = (float*)d_out;
    float* attn = out + (size_t)MROWS * DMODEL;

    ln_cast<<<16384, 256, 0, stream>>>(query, lng, lnb, qn,
                                       key, value, w_q, w_k, w_v, w_o,
                                       kb, vb, wqb, wkb, wvb, wob);

    qkv_proj<<<1536, 256, 0, stream>>>(qn, kb, vb, wqb, wkb, wvb, Qp, Kp, Vt);

    attn8<<<512, 256, 0, stream>>>(Qp, Kp, Vt, attn, oh);

    out_gemm<<<512, 256, 0, stream>>>(oh, wob, query, out);
}

// Round 23
// 261.104 us; speedup vs baseline: 1.0674x; 1.0674x over previous
//
#include <hip/hip_runtime.h>
#include <hip/hip_bf16.h>

// ---------------------------------------------------------------------------
// MultiheadAttention fused pipeline for MI355X (gfx950)  -- r21 session best
// B=2, S=S'=2048, H=16, D_MODEL=1024, dk=dv=64
// outputs: out [2,2048,1024] fp32, attn [2,16,2048,2048] fp32 (concat in d_out)
// ---------------------------------------------------------------------------

typedef __bf16 bf16x8 __attribute__((ext_vector_type(8)));
typedef __bf16 bf16x4 __attribute__((ext_vector_type(4)));
typedef float  f32x4  __attribute__((ext_vector_type(4)));
typedef float  f32x16 __attribute__((ext_vector_type(16)));

#define NUM_HEAD 16
#define SEQ 2048
#define DMODEL 1024
#define DK 64
#define MROWS 4096      // B*S
#define LOG2E 1.44269504088896340736f

__device__ __forceinline__ void gload_lds16(const void* g, void* l) {
    __builtin_amdgcn_global_load_lds((const __attribute__((address_space(1))) void*)g,
                                     (__attribute__((address_space(3))) void*)l, 16, 0, 0);
}

// ---------------------------------------------------------------------------
// Fused LayerNorm(query)->bf16  +  all fp32->bf16 casts, one dispatch.
// ---------------------------------------------------------------------------
__global__ __launch_bounds__(256) void ln_cast(const float* __restrict__ x,
                                               const float* __restrict__ g,
                                               const float* __restrict__ bt,
                                               __bf16* __restrict__ y,
                                               const float* __restrict__ key,
                                               const float* __restrict__ value,
                                               const float* __restrict__ wq,
                                               const float* __restrict__ wk,
                                               const float* __restrict__ wv,
                                               const float* __restrict__ wo,
                                               __bf16* kb, __bf16* vb, __bf16* wqb,
                                               __bf16* wkb, __bf16* wvb, __bf16* wob) {
    int tid = threadIdx.x;
    if (blockIdx.x < 4096) {
        int row = blockIdx.x;
        __shared__ float red[2][4];
        float4 v = ((const float4*)(x + (size_t)row * DMODEL))[tid];
        float s  = v.x + v.y + v.z + v.w;
        float sq = v.x * v.x + v.y * v.y + v.z * v.z + v.w * v.w;
        #pragma unroll
        for (int o = 32; o; o >>= 1) { s += __shfl_xor(s, o, 64); sq += __shfl_xor(sq, o, 64); }
        int wv_ = tid >> 6;
        if ((tid & 63) == 0) { red[0][wv_] = s; red[1][wv_] = sq; }
        __syncthreads();
        s  = red[0][0] + red[0][1] + red[0][2] + red[0][3];
        sq = red[1][0] + red[1][1] + red[1][2] + red[1][3];
        float mu  = s * (1.0f / DMODEL);
        float var = sq * (1.0f / DMODEL) - mu * mu;
        float rs  = rsqrtf(var + 1e-6f);
        float4 gg = ((const float4*)g)[tid];
        float4 bb = ((const float4*)bt)[tid];
        bf16x4 o;
        o[0] = (__bf16)((v.x - mu) * rs * gg.x + bb.x);
        o[1] = (__bf16)((v.y - mu) * rs * gg.y + bb.y);
        o[2] = (__bf16)((v.z - mu) * rs * gg.z + bb.z);
        o[3] = (__bf16)((v.w - mu) * rs * gg.w + bb.w);
        *(bf16x4*)&y[(size_t)row * DMODEL + tid * 4] = o;
    } else {
        int i = (blockIdx.x - 4096) * 256 + tid;    // float4 index, [0, 3145728)
        const float* src; __bf16* dst; int off;
        if (i < 1048576)      { src = key;   dst = kb;  off = i; }
        else if (i < 2097152) { src = value; dst = vb;  off = i - 1048576; }
        else if (i < 2359296) { src = wq;    dst = wqb; off = i - 2097152; }
        else if (i < 2621440) { src = wk;    dst = wkb; off = i - 2359296; }
        else if (i < 2883584) { src = wv;    dst = wvb; off = i - 2621440; }
        else                  { src = wo;    dst = wob; off = i - 2883584; }
        float4 v = ((const float4*)src)[off];
        bf16x4 o = {(__bf16)v.x, (__bf16)v.y, (__bf16)v.z, (__bf16)v.w};
        *(bf16x4*)&dst[(size_t)off * 4] = o;
    }
}

// ---------------------------------------------------------------------------
// Shared BK=64 XOR-swizzled GEMM K-loop (verified r15 core).
// ---------------------------------------------------------------------------
__device__ __forceinline__ void gemm_core64(const __bf16* __restrict__ Arow,
                                            const __bf16* __restrict__ Brow,
                                            __bf16 (*As)[64], __bf16 (*Bs)[64],
                                            int tid, int wr, int wc, int lr, int lg,
                                            f32x4 (&acc)[4][2]) {
    for (int kt = 0; kt < 1024; kt += 64) {
        __syncthreads();   // prior iter's LDS reads done
        #pragma unroll
        for (int c = 0; c < 4; ++c) {      // A: 128 rows x 64 cols
            int row = c * 32 + (tid >> 3);
            int col = ((tid & 7) ^ (row & 7)) * 8;
            gload_lds16(&Arow[(size_t)row * 1024 + kt + col], &As[row][(tid & 7) * 8]);
        }
        #pragma unroll
        for (int c = 0; c < 2; ++c) {      // B: 64 rows x 64 cols
            int row = c * 32 + (tid >> 3);
            int col = ((tid & 7) ^ (row & 7)) * 8;
            gload_lds16(&Brow[(size_t)row * 1024 + kt + col], &Bs[row][(tid & 7) * 8]);
        }
        __syncthreads();   // drains vmcnt+lgkm
        #pragma unroll
        for (int kk = 0; kk < 2; ++kk) {
            bf16x8 af[4], bg[2];
            #pragma unroll
            for (int m = 0; m < 4; ++m) {
                int row = wr + m * 16 + lr;
                int slot = (kk * 4 + lg) ^ (row & 7);
                af[m] = *(const bf16x8*)&As[row][slot * 8];
            }
            #pragma unroll
            for (int n = 0; n < 2; ++n) {
                int row = wc + n * 16 + lr;
                int slot = (kk * 4 + lg) ^ (row & 7);
                bg[n] = *(const bf16x8*)&Bs[row][slot * 8];
            }
            #pragma unroll
            for (int m = 0; m < 4; ++m)
                #pragma unroll
                for (int n = 0; n < 2; ++n)
                    acc[m][n] = __builtin_amdgcn_mfma_f32_16x16x32_bf16(af[m], bg[n], acc[m][n], 0, 0, 0);
        }
    }
}

// ---------------------------------------------------------------------------
// Fused Q/K/V projections, 128x64 tiles -> 3 x 512 = 1536 blocks (6/CU),
// XCD-chunked block swizzle.  mode 0: Q scaled (1/8)*log2e; 1: K; 2: V^T.
// ---------------------------------------------------------------------------
__global__ __launch_bounds__(256) void qkv_proj(const __bf16* __restrict__ qn,
                                                const __bf16* __restrict__ kb,
                                                const __bf16* __restrict__ vb,
                                                const __bf16* __restrict__ wqb,
                                                const __bf16* __restrict__ wkb,
                                                const __bf16* __restrict__ wvb,
                                                __bf16* __restrict__ Qp,
                                                __bf16* __restrict__ Kp,
                                                __bf16* __restrict__ Vt) {
    __shared__ __bf16 As[128][64];   // 16 KB
    __shared__ __bf16 Bs[64][64];    //  8 KB
    int bid = blockIdx.x;
    int wgid = (bid & 7) * 192 + (bid >> 3);  // XCD-chunked (1536/8 = 192)
    int mode = wgid >> 9;                     // 0,1,2
    int t = wgid & 511;
    int tm = t >> 4, tn = t & 15;             // 32 x 16 tiles (M=4096, N=1024)
    int tid = threadIdx.x, lane = tid & 63, wv = tid >> 6;
    int wr = (wv >> 1) * 64, wc = (wv & 1) * 32;
    int lr = lane & 15, lg = lane >> 4;

    const __bf16* A = (mode == 0) ? qn : (mode == 1) ? kb : vb;
    const __bf16* W = (mode == 0) ? wqb : (mode == 1) ? wkb : wvb;

    f32x4 acc[4][2] = {};
    gemm_core64(A + (size_t)(tm * 128) * 1024, W + (size_t)(tn * 64) * 1024,
                As, Bs, tid, wr, wc, lr, lg, acc);

    if (mode < 2) {
        float scale = (mode == 0) ? (0.125f * LOG2E) : 1.0f;
        __bf16* C = (mode == 0) ? Qp : Kp;
        #pragma unroll
        for (int m = 0; m < 4; ++m)
            #pragma unroll
            for (int n = 0; n < 2; ++n)
                #pragma unroll
                for (int r = 0; r < 4; ++r) {
                    int grow = tm * 128 + wr + m * 16 + lg * 4 + r;
                    int gcol = tn * 64 + wc + n * 16 + lr;
                    int b = grow >> 11, ss = grow & 2047, h = gcol >> 6, d = gcol & 63;
                    C[((size_t)(b * NUM_HEAD + h) * SEQ + ss) * DK + d] = (__bf16)(acc[m][n][r] * scale);
                }
    } else {
        #pragma unroll
        for (int m = 0; m < 4; ++m)
            #pragma unroll
            for (int n = 0; n < 2; ++n)
                #pragma unroll
                for (int r = 0; r < 4; ++r) {
                    int grow = tm * 128 + wr + m * 16 + lg * 4 + r;
                    int gcol = tn * 64 + wc + n * 16 + lr;
                    int b = grow >> 11, ss = grow & 2047, h = gcol >> 6, d = gcol & 63;
                    Vt[((size_t)(b * NUM_HEAD + h) * DK + d) * SEQ + ss] = (__bf16)acc[m][n][r];
                }
    }
}

// ---------------------------------------------------------------------------
// Output projection + residual, 128x64 tiles -> 512 blocks (2/CU), XCD swz.
// ---------------------------------------------------------------------------
__global__ __launch_bounds__(256) void out_gemm(const __bf16* __restrict__ A,
                                                const __bf16* __restrict__ Bw,
                                                const float* __restrict__ residual,
                                                float* __restrict__ out) {
    __shared__ __bf16 As[128][64];
    __shared__ __bf16 Bs[64][64];
    int bid = blockIdx.x;
    int wgid = (bid & 7) * 64 + (bid >> 3);   // XCD-chunked
    int tm = wgid >> 4, tn = wgid & 15;
    int tid = threadIdx.x, lane = tid & 63, wv = tid >> 6;
    int wr = (wv >> 1) * 64, wc = (wv & 1) * 32;
    int lr = lane & 15, lg = lane >> 4;

    f32x4 acc[4][2] = {};
    gemm_core64(A + (size_t)(tm * 128) * 1024, Bw + (size_t)(tn * 64) * 1024,
                As, Bs, tid, wr, wc, lr, lg, acc);

    #pragma unroll
    for (int m = 0; m < 4; ++m)
        #pragma unroll
        for (int n = 0; n < 2; ++n)
            #pragma unroll
            for (int r = 0; r < 4; ++r) {
                int grow = tm * 128 + wr + m * 16 + lg * 4 + r;
                int gcol = tn * 64 + wc + n * 16 + lr;
                size_t idx = (size_t)grow * DMODEL + gcol;
                out[idx] = acc[m][n][r] + residual[idx];
            }
}

// ---------------------------------------------------------------------------
// Attention, LDS-staged K/V (attn8), m==0 softmax (r21 session best).
// PASS A uses the FULL 64KB as a 2 x 256-key K double-buffer (K4 aliases
// Ks+Vs): 8 rounds.  PASS B: 128-key chunks, Ks+Vs double-buffered.
// gload_lds rule: per-wave LDS dest contiguous lane*16 (m104).
// Swizzle: phys slot = logical ^ (row&7) on both source and read (rule #21).
// ---------------------------------------------------------------------------
__global__ __launch_bounds__(256) void attn8(const __bf16* __restrict__ Qp,
                                             const __bf16* __restrict__ Kp,
                                             const __bf16* __restrict__ Vt,
                                             float* __restrict__ attn_out,
                                             __bf16* __restrict__ out_heads) {
    __shared__ __bf16 smem_raw[32768];  // 64 KB

    __bf16 (*Ks)[128][64] = (__bf16 (*)[128][64])smem_raw;              // pass B
    __bf16 (*Vs)[64][128] = (__bf16 (*)[64][128])(smem_raw + 16384);    // pass B
    __bf16 (*K4)[256][64] = (__bf16 (*)[256][64])smem_raw;              // pass A

    int bid = blockIdx.x;
    int wid = (bid & 7) * 64 + (bid >> 3);    // 512 blocks, XCD-chunked (512%8==0)
    int bh = wid >> 4;                        // [0,32)
    int qbase = (wid & 15) * 128;             // block q-rows [qbase, qbase+128)
    int tid = threadIdx.x, lane = tid & 63, wv = tid >> 6;
    int l31 = lane & 31, hi = lane >> 5;
    int qw = qbase + wv * 32;                 // wave's 32 q-rows

    const __bf16* Qh = Qp + ((size_t)bh * SEQ + qw) * DK;
    const __bf16* Kh = Kp + (size_t)bh * SEQ * DK;
    const __bf16* Vh = Vt + (size_t)bh * DK * SEQ;

    bf16x8 qf[4];
    #pragma unroll
    for (int s = 0; s < 4; ++s)
        qf[s] = *(const bf16x8*)&Qh[(size_t)l31 * DK + s * 16 + hi * 8];

    // ---- staging lambdas; per-wave LDS dest = lane*16 contiguous ----
    int krow = tid >> 3, ksc = tid & 7;       // K: 32 rows/step x 8 slots
    auto stageK = [&](int buf, int kc) {      // pass B: 128-key chunk
        #pragma unroll
        for (int j = 0; j < 4; ++j) {
            int row = j * 32 + krow;
            gload_lds16(&Kh[(size_t)(kc + row) * DK + ((ksc ^ (row & 7)) * 8)],
                        &Ks[buf][row][ksc * 8]);
        }
    };
    auto stageK4 = [&](int buf, int kc) {     // pass A: 256-key chunk
        #pragma unroll
        for (int j = 0; j < 8; ++j) {
            int row = j * 32 + krow;
            gload_lds16(&Kh[(size_t)(kc + row) * DK + ((ksc ^ (row & 7)) * 8)],
                        &K4[buf][row][ksc * 8]);
        }
    };
    int vrow16 = tid >> 4, vslot = tid & 15;  // V: 16 rows/step x 16 slots
    auto stageV = [&](int buf, int kc) {
        #pragma unroll
        for (int j = 0; j < 4; ++j) {
            int row = j * 16 + vrow16;
            gload_lds16(&Vh[(size_t)row * SEQ + kc + ((vslot ^ (row & 7)) * 8)],
                        &Vs[buf][row][vslot * 8]);
        }
    };
    auto readK = [&](int buf, int row, int s) -> bf16x8 {
        int slot = (2 * s + hi) ^ (row & 7);
        return *(const bf16x8*)&Ks[buf][row][slot * 8];
    };
    auto readK4 = [&](int buf, int row, int s) -> bf16x8 {
        int slot = (2 * s + hi) ^ (row & 7);
        return *(const bf16x8*)&K4[buf][row][slot * 8];
    };
    auto readV = [&](int buf, int drow, int g) -> bf16x8 {
        int slot = g ^ (drow & 7);
        return *(const bf16x8*)&Vs[buf][drow][slot * 8];
    };

    // ---- pass A: lsum over all 2048 keys (m == 0), 256-key chunks ----
    float lsum = 0.f;
    auto tileA = [&](int buf, int toff) {
        bf16x8 kf[4];
        #pragma unroll
        for (int s = 0; s < 4; ++s) kf[s] = readK4(buf, toff + l31, s);
        f32x16 dd;
        #pragma unroll
        for (int r = 0; r < 16; ++r) dd[r] = 0.f;
        __builtin_amdgcn_s_setprio(1);
        #pragma unroll
        for (int s = 0; s < 4; ++s)
            dd = __builtin_amdgcn_mfma_f32_32x32x16_bf16(kf[s], qf[s], dd, 0, 0, 0);
        __builtin_amdgcn_s_setprio(0);
        float es[4] = {0.f, 0.f, 0.f, 0.f};
        #pragma unroll
        for (int r = 0; r < 16; ++r) es[r & 3] += exp2f(dd[r]);
        lsum += (es[0] + es[1]) + (es[2] + es[3]);
    };

    stageK4(0, 0);
    for (int c = 0; c < 8; ++c) {
        __syncthreads();                       // stage of buf (c&1) complete
        if (c + 1 < 8) stageK4((c + 1) & 1, (c + 1) * 256);
        #pragma unroll
        for (int t = 0; t < 8; ++t) tileA(c & 1, t * 32);
        __syncthreads();                       // reads done before re-stage
    }
    lsum += __shfl_xor(lsum, 32, 64);          // merge interleaved key-halves
    float invl = 1.0f / lsum;

    // ---- pass B: normalized P write + PV ----
    float* attn_base = attn_out + ((size_t)bh * SEQ + qw) * SEQ;
    f32x16 o0, o1;
    #pragma unroll
    for (int r = 0; r < 16; ++r) { o0[r] = 0.f; o1[r] = 0.f; }

    auto tileB = [&](int buf, int kglob, int toff) {
        bf16x8 kf[4];
        #pragma unroll
        for (int s = 0; s < 4; ++s) kf[s] = readK(buf, toff + l31, s);
        f32x16 dd;
        #pragma unroll
        for (int r = 0; r < 16; ++r) dd[r] = 0.f;
        __builtin_amdgcn_s_setprio(1);
        #pragma unroll
        for (int s = 0; s < 4; ++s)
            dd = __builtin_amdgcn_mfma_f32_32x32x16_bf16(kf[s], qf[s], dd, 0, 0, 0);
        __builtin_amdgcn_s_setprio(0);

        int gb = toff >> 3;   // V slot base within chunk (0,4,8,12)
        bf16x8 vf00 = readV(buf, l31,      gb + hi);
        bf16x8 vf01 = readV(buf, 32 + l31, gb + hi);
        bf16x8 vf10 = readV(buf, l31,      gb + 2 + hi);
        bf16x8 vf11 = readV(buf, 32 + l31, gb + 2 + hi);

        float p[16];
        #pragma unroll
        for (int r = 0; r < 16; ++r) p[r] = exp2f(dd[r]) * invl;

        int k0 = kglob + toff;
        #pragma unroll
        for (int q4 = 0; q4 < 4; ++q4) {
            f32x4 v4 = {p[4 * q4], p[4 * q4 + 1], p[4 * q4 + 2], p[4 * q4 + 3]};
            *(f32x4*)&attn_base[(size_t)l31 * SEQ + k0 + 8 * q4 + 4 * hi] = v4;
        }

        unsigned int w[8];
        #pragma unroll
        for (int i = 0; i < 8; ++i) {
            union { __bf16 h[2]; unsigned int u; } bw;
            bw.h[0] = (__bf16)p[2 * i];
            bw.h[1] = (__bf16)p[2 * i + 1];
            w[i] = bw.u;
        }
        __builtin_amdgcn_s_setprio(1);
        {   // slot 0 (keys k0..k0+15)
            unsigned int a0 = w[0], a1 = w[1], a2 = w[2], a3 = w[3];
            asm volatile("v_permlane32_swap_b32 %0, %1" : "+v"(a0), "+v"(a2));
            asm volatile("v_permlane32_swap_b32 %0, %1" : "+v"(a1), "+v"(a3));
            union { unsigned int u[4]; bf16x8 v; } pa;
            pa.u[0] = a0; pa.u[1] = a1; pa.u[2] = a2; pa.u[3] = a3;
            o0 = __builtin_amdgcn_mfma_f32_32x32x16_bf16(pa.v, vf00, o0, 0, 0, 0);
            o1 = __builtin_amdgcn_mfma_f32_32x32x16_bf16(pa.v, vf01, o1, 0, 0, 0);
        }
        {   // slot 1 (keys k0+16..k0+31)
            unsigned int a0 = w[4], a1 = w[5], a2 = w[6], a3 = w[7];
            asm volatile("v_permlane32_swap_b32 %0, %1" : "+v"(a0), "+v"(a2));
            asm volatile("v_permlane32_swap_b32 %0, %1" : "+v"(a1), "+v"(a3));
            union { unsigned int u[4]; bf16x8 v; } pa;
            pa.u[0] = a0; pa.u[1] = a1; pa.u[2] = a2; pa.u[3] = a3;
            o0 = __builtin_amdgcn_mfma_f32_32x32x16_bf16(pa.v, vf10, o0, 0, 0, 0);
            o1 = __builtin_amdgcn_mfma_f32_32x32x16_bf16(pa.v, vf11, o1, 0, 0, 0);
        }
        __builtin_amdgcn_s_setprio(0);
    };

    stageK(0, 0);
    stageV(0, 0);
    for (int c = 0; c < 16; ++c) {
        __syncthreads();                       // stage of buf (c&1) complete
        if (c + 1 < 16) { stageK((c + 1) & 1, (c + 1) * 128); stageV((c + 1) & 1, (c + 1) * 128); }
        tileB(c & 1, c * 128, 0);
        tileB(c & 1, c * 128, 32);
        tileB(c & 1, c * 128, 64);
        tileB(c & 1, c * 128, 96);
        __syncthreads();                       // reads done before re-stage
    }

    // ---- O write: P already normalized in tileB -> no invl here ----
    int b = bh >> 4, h = bh & 15;
    #pragma unroll
    for (int r = 0; r < 16; ++r) {
        int q = (r & 3) + 8 * (r >> 2) + 4 * hi;
        __bf16* orow = &out_heads[((size_t)(b * SEQ + qw + q)) * DMODEL + h * DK];
        orow[l31]      = (__bf16)o0[r];
        orow[32 + l31] = (__bf16)o1[r];
    }
}

// ---------------------------------------------------------------------------
extern "C" void kernel_launch(void* const* d_in, const int* in_sizes, int n_in,
                              void* d_out, int out_size, void* d_ws, size_t ws_size,
                              hipStream_t stream) {
    const float* query = (const float*)d_in[0];
    const float* key   = (const float*)d_in[1];
    const float* value = (const float*)d_in[2];
    const float* w_q   = (const float*)d_in[3];
    const float* w_k   = (const float*)d_in[4];
    const float* w_v   = (const float*)d_in[5];
    const float* w_o   = (const float*)d_in[6];
    const float* lng   = (const float*)d_in[7];
    const float* lnb   = (const float*)d_in[8];

    char* ws = (char*)d_ws;
    __bf16* qn  = (__bf16*)(ws);                    // 8 MB  LN(query) bf16
    __bf16* kb  = (__bf16*)(ws + ( 8u << 20));      // 8 MB  key bf16
    __bf16* vb  = (__bf16*)(ws + (16u << 20));      // 8 MB  value bf16
    __bf16* wqb = (__bf16*)(ws + (24u << 20));      // 2 MB
    __bf16* wkb = (__bf16*)(ws + (26u << 20));      // 2 MB
    __bf16* wvb = (__bf16*)(ws + (28u << 20));      // 2 MB
    __bf16* wob = (__bf16*)(ws + (30u << 20));      // 2 MB
    __bf16* Qp  = (__bf16*)(ws + (32u << 20));      // 8 MB  [b,h,s,64] (x(1/8)*log2e)
    __bf16* Kp  = (__bf16*)(ws + (40u << 20));      // 8 MB  [b,h,s,64]
    __bf16* Vt  = (__bf16*)(ws + (48u << 20));      // 8 MB  [b,h,64,s']
    __bf16* oh  = (__bf16*)(ws + (56u << 20));      // 8 MB  attention out [4096,1024]

    float* out  = (float*)d_out;
    float* attn = out + (size_t)MROWS * DMODEL;

    ln_cast<<<16384, 256, 0, stream>>>(query, lng, lnb, qn,
                                       key, value, w_q, w_k, w_v, w_o,
                                       kb, vb, wqb, wkb, wvb, wob);

    qkv_proj<<<1536, 256, 0, stream>>>(qn, kb, vb, wqb, wkb, wvb, Qp, Kp, Vt);

    attn8<<<512, 256, 0, stream>>>(Qp, Kp, Vt, attn, oh);

    out_gemm<<<512, 256, 0, stream>>>(oh, wob, query, out);
}